// Round 3
// baseline (268.036 us; speedup 1.0000x reference)
//
#include <hip/hip_runtime.h>
#include <hip/hip_bf16.h>

#define NQ   50000
#define NKV  50000
#define CC   128
#define GG   8
#define SS   16
#define CSH  16

typedef short    bf16x8 __attribute__((ext_vector_type(8)));
typedef float    f32x4  __attribute__((ext_vector_type(4)));
typedef unsigned u32x4  __attribute__((ext_vector_type(4)));
typedef unsigned u32x2  __attribute__((ext_vector_type(2)));
typedef int      i32x4  __attribute__((ext_vector_type(4)));

__device__ __forceinline__ float bf_lo(unsigned u){ union{unsigned x; float f;} v; v.x = u << 16;        return v.f; }
__device__ __forceinline__ float bf_hi(unsigned u){ union{unsigned x; float f;} v; v.x = u & 0xffff0000u; return v.f; }
__device__ __forceinline__ unsigned short f2bfu(float f){
    __hip_bfloat16 h = __float2bfloat16(f);
    return *reinterpret_cast<unsigned short*>(&h);
}
__device__ __forceinline__ short f2bfs(float f){
    __hip_bfloat16 h = __float2bfloat16(f);
    return *reinterpret_cast<short*>(&h);
}

// Load 16 contiguous bf16 (32B, >=16B aligned) -> 16 fp32
__device__ __forceinline__ void load16bf(const __hip_bfloat16* ptr, float* o){
    const u32x4* p4 = reinterpret_cast<const u32x4*>(ptr);
    u32x4 a = p4[0]; u32x4 b = p4[1];
    o[0]=bf_lo(a[0]);  o[1]=bf_hi(a[0]);  o[2]=bf_lo(a[1]);  o[3]=bf_hi(a[1]);
    o[4]=bf_lo(a[2]);  o[5]=bf_hi(a[2]);  o[6]=bf_lo(a[3]);  o[7]=bf_hi(a[3]);
    o[8]=bf_lo(b[0]);  o[9]=bf_hi(b[0]);  o[10]=bf_lo(b[1]); o[11]=bf_hi(b[1]);
    o[12]=bf_lo(b[2]); o[13]=bf_hi(b[2]); o[14]=bf_lo(b[3]); o[15]=bf_hi(b[3]);
}

// Lazy dot: 16B of raw bf16 K against 8 fp32 q channels; accumulates sumk too.
__device__ __forceinline__ float dot8_lazy(const u32x4& a, const float* q8, float& sumk){
    float d = 0.f;
    #pragma unroll
    for (int j = 0; j < 4; ++j) {
        const float lo = bf_lo(a[j]), hi = bf_hi(a[j]);
        d    += lo * q8[2*j] + hi * q8[2*j+1];
        sumk += lo + hi;
    }
    return d;
}
// Lazy accumulate: 16B of raw bf16 V into 8 fp32 acc channels.
__device__ __forceinline__ void acc8_lazy(const u32x4& a, float corr, float w, float* acc8){
    #pragma unroll
    for (int j = 0; j < 4; ++j) {
        acc8[2*j]   = acc8[2*j]  * corr + w * bf_lo(a[j]);
        acc8[2*j+1] = acc8[2*j+1]* corr + w * bf_hi(a[j]);
    }
}

// Load 8 contiguous f32 (32B), convert to bf16x8 fragment
__device__ __forceinline__ bf16x8 cvt8(const float* p){
    const f32x4* q = reinterpret_cast<const f32x4*>(p);
    f32x4 u = q[0], v = q[1];
    bf16x8 r;
    r[0]=f2bfs(u[0]); r[1]=f2bfs(u[1]); r[2]=f2bfs(u[2]); r[3]=f2bfs(u[3]);
    r[4]=f2bfs(v[0]); r[5]=f2bfs(v[1]); r[6]=f2bfs(v[2]); r[7]=f2bfs(v[3]);
    return r;
}

// ---------------------------------------------------------------------------
// Kernel 1: Q/K/V projections, gridDim.y = 3 selects projection (0=Q,1=K,2=V).
// UNCHANGED from round 2 (the y-split gained ~8 us by side-attribution).
// ---------------------------------------------------------------------------
__global__ __launch_bounds__(256) void qkv_gemm(
    const float* __restrict__ x,
    const float* __restrict__ x2,
    const float* __restrict__ Wq, const float* __restrict__ Wk,
    const float* __restrict__ Wv,
    const float* __restrict__ bq, const float* __restrict__ bk,
    const float* __restrict__ bv,
    __hip_bfloat16* __restrict__ Qf,     // (NQ, 128)
    __hip_bfloat16* __restrict__ KVf)    // (NKV, 256) interleaved K|V
{
    __shared__ short lds16[16384];   // 32 KB

    const int tid  = threadIdx.x;
    const int wave = tid >> 6;
    const int lane = tid & 63;
    const int r    = lane & 15;
    const int kq   = lane >> 4;
    const int base = blockIdx.x * 128 + wave * 32;   // this wave's 32 rows
    const int proj = blockIdx.y;                     // 0=Q 1=K 2=V (uniform)

    const float* src  = (proj == 0) ? x  : x2;
    const float* W    = (proj == 0) ? Wq : (proj == 1 ? Wk : Wv);
    const float* bias = (proj == 0) ? bq : (proj == 1 ? bk : bv);
    short* dstb   = (proj == 0) ? (short*)Qf : (short*)KVf;
    const int dstride = (proj == 0) ? CC : 2 * CC;
    const int hoff    = (proj == 2) ? CC : 0;

    // load this wave's 32 source rows as B-fragments (2 m-tiles x 4 k-blocks)
    bf16x8 bfrag[2][4];
    #pragma unroll
    for (int mt = 0; mt < 2; ++mt) {
        int row = base + mt * 16 + r;
        if (row >= NQ) row = NQ - 1;           // clamp; stores guarded
        const float* xr = src + (size_t)row * CC + kq * 8;
        #pragma unroll
        for (int kb = 0; kb < 4; ++kb)
            bfrag[mt][kb] = cvt8(xr + kb * 32);
    }

    // stage one 128x128 f32 W into LDS (bf16, MFMA A-fragment order)
    #pragma unroll
    for (int i = 0; i < 8; ++i) {
        const int o   = i * 2048 + tid * 8;    // linear f32 offset in W
        const bf16x8 v = cvt8(W + o);
        const int row = o >> 7, col = o & 127;
        const int lchunk = (((row >> 4) * 4 + (col >> 5)) << 6)
                         + (((col >> 3) & 3) << 4) + (row & 15);
        *reinterpret_cast<bf16x8*>(&lds16[lchunk * 8]) = v;
    }
    __syncthreads();

    // 8 column tiles: LDS A-frags x register B-frags -> 2x f32x4 acc -> store
    #pragma unroll
    for (int t = 0; t < 8; ++t) {
        bf16x8 af[4];
        #pragma unroll
        for (int kb = 0; kb < 4; ++kb)
            af[kb] = *reinterpret_cast<const bf16x8*>(
                &lds16[(((t * 4 + kb) << 6) + lane) * 8]);

        f32x4 acc0 = {0.f,0.f,0.f,0.f}, acc1 = {0.f,0.f,0.f,0.f};
        #pragma unroll
        for (int kb = 0; kb < 4; ++kb) {
            acc0 = __builtin_amdgcn_mfma_f32_16x16x32_bf16(af[kb], bfrag[0][kb], acc0, 0, 0, 0);
            acc1 = __builtin_amdgcn_mfma_f32_16x16x32_bf16(af[kb], bfrag[1][kb], acc1, 0, 0, 0);
        }

        const f32x4 bi = *reinterpret_cast<const f32x4*>(bias + t * 16 + kq * 4);
        #pragma unroll
        for (int mt = 0; mt < 2; ++mt) {
            const int row = base + mt * 16 + r;
            if (row < NQ) {
                const f32x4 a = mt ? acc1 : acc0;
                u32x2 pk;
                pk[0] = (unsigned)f2bfu(a[0] + bi[0]) | ((unsigned)f2bfu(a[1] + bi[1]) << 16);
                pk[1] = (unsigned)f2bfu(a[2] + bi[2]) | ((unsigned)f2bfu(a[3] + bi[3]) << 16);
                *reinterpret_cast<u32x2*>(
                    dstb + (size_t)row * dstride + hoff + t * 16 + kq * 4) = pk;
            }
        }
    }
}

// ---------------------------------------------------------------------------
// Kernel 2: fused gather + positional MLP + grouped attention.
// Round-3 changes (r2 post-mortem: split-S lost to r0 because per-thread
// preamble VMEM doubled; loads still only ~1-2 in flight per wave at 52 VGPR):
//  a. LDS per-g param table for W2/b2 (8 floats/g, 8 threads fill + barrier)
//     -> removes ~8 VMEM/thread of duplicated preamble.
//  b. 2-stream in-register split: each thread = 2 independent online softmaxes
//     over 4 neighbors (A: nbr[0..3], B: nbr[4..7]); BOTH streams' gathers
//     issue at the top of each loop iteration (8 KV + 2 p2 loads in flight,
//     ~2x per-wave MLP), serial exp chain 8 -> 4. In-register A/B merge, then
//     the proven cross-lane h-merge.
//  c. Lazy bf16 conversion: gathered K/V stay raw u32x4 until consumed in
//     dot/acc (transient floats) -> clustered loads cost 16 raw regs, not 64
//     floats (guards against the r1 156-VGPR blowup).
// Kept: online max-shifted exp (PE term ~250 overflows unshifted), logit
// algebra d = dot + prq*sumk + prk*sumq + 16*prk*prq, exact 3125-block grid
// (no early return -> barrier-safe).
// ---------------------------------------------------------------------------
__global__ __launch_bounds__(256) void attn_kernel(
    const float* __restrict__ p,        // (NQ,3)
    const float* __restrict__ p2,       // (NKV,3)
    const int*   __restrict__ idx,      // (NQ,SS)
    const float* __restrict__ W1,       // (3,3)
    const float* __restrict__ b1,       // (3,)
    const float* __restrict__ bn_gamma,
    const float* __restrict__ bn_beta,
    const float* __restrict__ bn_mean,
    const float* __restrict__ bn_var,
    const float* __restrict__ W2,       // (16,3)
    const float* __restrict__ b2,       // (16,)
    const __hip_bfloat16* __restrict__ Qf,   // (NQ,128) bf16
    const __hip_bfloat16* __restrict__ KVf,  // (NKV,256) bf16 interleaved
    float* __restrict__ out)            // (NQ,CC) f32
{
    __shared__ __align__(16) float gtab[8][8];  // {w2q0..2, w2k0..2, b2q, b2k}

    if (threadIdx.x < 8) {
        const int gg = threadIdx.x;
        gtab[gg][0] = W2[gg*3+0];
        gtab[gg][1] = W2[gg*3+1];
        gtab[gg][2] = W2[gg*3+2];
        gtab[gg][3] = W2[(gg+8)*3+0];
        gtab[gg][4] = W2[(gg+8)*3+1];
        gtab[gg][5] = W2[(gg+8)*3+2];
        gtab[gg][6] = b2[gg];
        gtab[gg][7] = b2[gg+8];
    }

    const int tid = blockIdx.x * 256 + threadIdx.x;   // 800000 threads exactly
    const int n = tid >> 4;
    const int g = (tid >> 1) & 7;
    const int h = tid & 1;              // neighbor-half: s in [h*8, h*8+8)

    // --- fold BN into the 3x3 conv (uniform: scalar loads/ops) ---
    float fw1[3][3], fb1[3];
    #pragma unroll
    for (int j = 0; j < 3; ++j) {
        const float sc = bn_gamma[j] * rsqrtf(bn_var[j] + 1e-5f);
        #pragma unroll
        for (int k = 0; k < 3; ++k) fw1[j][k] = W1[j*3 + k] * sc;
        fb1[j] = (b1[j] - bn_mean[j]) * sc + bn_beta[j];
    }

    const float px = p[(size_t)n*3+0];
    const float py = p[(size_t)n*3+1];
    const float pz = p[(size_t)n*3+2];

    // --- this half's 8 neighbor indices (32B aligned) ---
    int nbr[8];
    {
        const i32x4* ip = reinterpret_cast<const i32x4*>(idx + (size_t)n * SS + h * 8);
        i32x4 i0 = ip[0], i1 = ip[1];
        nbr[0]=i0[0]; nbr[1]=i0[1]; nbr[2]=i0[2]; nbr[3]=i0[3];
        nbr[4]=i1[0]; nbr[5]=i1[1]; nbr[6]=i1[2]; nbr[7]=i1[3];
    }

    // --- query fragment for this group ---
    float q[CSH];
    load16bf(Qf + (size_t)n * CC + g * CSH, q);
    float sumq = 0.f;
    #pragma unroll
    for (int c = 0; c < CSH; ++c) sumq += q[c];

    __syncthreads();                    // gtab ready
    const f32x4 t0 = *reinterpret_cast<const f32x4*>(&gtab[g][0]);
    const f32x4 t1 = *reinterpret_cast<const f32x4*>(&gtab[g][4]);
    const float w2q0 = t0[0], w2q1 = t0[1], w2q2 = t0[2];
    const float w2k0 = t0[3], w2k1 = t1[0], w2k2 = t1[1];
    const float b2q  = t1[2], b2k  = t1[3];

    // --- two independent online-softmax streams ---
    float accA[CSH], accB[CSH];
    #pragma unroll
    for (int c = 0; c < CSH; ++c) { accA[c] = 0.f; accB[c] = 0.f; }
    float sumA = 0.f, sumB = 0.f;
    float mA = -3.0e38f, mB = -3.0e38f;

    auto consume = [&](const u32x4& k0, const u32x4& k1,
                       const u32x4& v0, const u32x4& v1,
                       float rx, float ry, float rz,
                       float (&acc)[CSH], float& m, float& sum) {
        const float h0 = fmaxf(fw1[0][0]*rx + fw1[0][1]*ry + fw1[0][2]*rz + fb1[0], 0.f);
        const float h1 = fmaxf(fw1[1][0]*rx + fw1[1][1]*ry + fw1[1][2]*rz + fb1[1], 0.f);
        const float h2 = fmaxf(fw1[2][0]*rx + fw1[2][1]*ry + fw1[2][2]*rz + fb1[2], 0.f);
        const float prq = w2q0*h0 + w2q1*h1 + w2q2*h2 + b2q;
        const float prk = w2k0*h0 + w2k1*h1 + w2k2*h2 + b2k;

        float sumk = 0.f;
        const float dot = dot8_lazy(k0, q, sumk) + dot8_lazy(k1, q + 8, sumk);
        const float d = (dot + prq*sumk + prk*sumq + 16.f*prk*prq) * 0.25f;

        const float mnew = fmaxf(m, d);
        const float corr = __expf(m - mnew);   // 1.0 when max unchanged
        const float w    = __expf(d - mnew);
        sum = sum * corr + w;
        acc8_lazy(v0, corr, w, acc);
        acc8_lazy(v1, corr, w, acc + 8);
        m = mnew;
    };

    #pragma unroll
    for (int s = 0; s < 4; ++s) {
        const int iA = nbr[s], iB = nbr[s + 4];
        const u32x4* kvA = reinterpret_cast<const u32x4*>(KVf + (size_t)iA * (2*CC) + g * CSH);
        const u32x4* kvB = reinterpret_cast<const u32x4*>(KVf + (size_t)iB * (2*CC) + g * CSH);
        // issue BOTH streams' gathers up front (raw, no conversion)
        const u32x4 kA0 = kvA[0], kA1 = kvA[1], vA0 = kvA[16], vA1 = kvA[17];
        const u32x4 kB0 = kvB[0], kB1 = kvB[1], vB0 = kvB[16], vB1 = kvB[17];
        const float rAx = p2[(size_t)iA*3+0] - px;
        const float rAy = p2[(size_t)iA*3+1] - py;
        const float rAz = p2[(size_t)iA*3+2] - pz;
        const float rBx = p2[(size_t)iB*3+0] - px;
        const float rBy = p2[(size_t)iB*3+1] - py;
        const float rBz = p2[(size_t)iB*3+2] - pz;

        consume(kA0, kA1, vA0, vA1, rAx, rAy, rAz, accA, mA, sumA);
        consume(kB0, kB1, vB0, vB1, rBx, rBy, rBz, accB, mB, sumB);
    }

    // --- in-register A/B merge ---
    const float M0 = fmaxf(mA, mB);
    const float cA = __expf(mA - M0), cB = __expf(mB - M0);
    const float sum = sumA * cA + sumB * cB;
    float acc[CSH];
    #pragma unroll
    for (int c = 0; c < CSH; ++c) acc[c] = accA[c] * cA + accB[c] * cB;

    // --- merge the two halves (partner = lane^1, same n,g) ---
    const float mo = __shfl_xor(M0, 1);
    const float M  = fmaxf(M0, mo);
    const float cs = __expf(M0 - M);           // my scale
    const float co = __expf(mo - M);           // partner's scale
    const float so = __shfl_xor(sum, 1);
    const float inv = 1.f / (sum * cs + so * co);
    const float mycs = cs * inv, pco = co * inv;

    // each lane stores channels [h*8, h*8+8): one shfl_xor both transmits what
    // partner needs and receives what I need (all static indices).
    float o[8];
    #pragma unroll
    for (int j = 0; j < 8; ++j) {
        const float send = h ? acc[j] : acc[j + 8];
        const float recv = __shfl_xor(send, 1);
        const float own  = h ? acc[j + 8] : acc[j];
        o[j] = own * mycs + recv * pco;
    }

    // --- store 8 f32 (32B; 16 lanes of one n cover 512B contiguous) ---
    f32x4* op = reinterpret_cast<f32x4*>(out + (size_t)n * CC + g * CSH + h * 8);
    f32x4 o0 = {o[0], o[1], o[2], o[3]};
    f32x4 o1 = {o[4], o[5], o[6], o[7]};
    op[0] = o0; op[1] = o1;
}

// ---------------------------------------------------------------------------
extern "C" void kernel_launch(void* const* d_in, const int* in_sizes, int n_in,
                              void* d_out, int out_size, void* d_ws, size_t ws_size,
                              hipStream_t stream) {
    const float* p   = (const float*)d_in[0];
    const float* x   = (const float*)d_in[1];
    const float* p2  = (const float*)d_in[2];
    const float* x2  = (const float*)d_in[3];
    const int*   idx = (const int*)d_in[4];
    const float* Wq  = (const float*)d_in[5];
    const float* bq  = (const float*)d_in[6];
    const float* Wk  = (const float*)d_in[7];
    const float* bk  = (const float*)d_in[8];
    const float* Wv  = (const float*)d_in[9];
    const float* bv  = (const float*)d_in[10];
    const float* W1  = (const float*)d_in[11];
    const float* b1  = (const float*)d_in[12];
    const float* bng = (const float*)d_in[13];
    const float* bnb = (const float*)d_in[14];
    const float* bnm = (const float*)d_in[15];
    const float* bnv = (const float*)d_in[16];
    const float* W2  = (const float*)d_in[17];
    const float* b2  = (const float*)d_in[18];
    float* out = (float*)d_out;

    // workspace: Qf (12.8 MB) | KVf interleaved (25.6 MB)
    __hip_bfloat16* Qf  = (__hip_bfloat16*)d_ws;
    __hip_bfloat16* KVf = Qf + (size_t)NQ * CC;

    // 50000 rows / 128 rows-per-block = 391 blocks; y-dim = projection (Q,K,V)
    qkv_gemm<<<dim3(391, 3), 256, 0, stream>>>(
        x, x2, Wq, Wk, Wv, bq, bk, bv, Qf, KVf);

    // 50000 * 8 groups * 2 halves = 800000 threads = 3125 blocks exactly
    attn_kernel<<<3125, 256, 0, stream>>>(
        p, p2, idx, W1, b1, bng, bnb, bnm, bnv, W2, b2, Qf, KVf, out);
}

// Round 4
// 223.264 us; speedup vs baseline: 1.2005x; 1.2005x over previous
//
#include <hip/hip_runtime.h>
#include <hip/hip_bf16.h>

#define NQ   50000
#define NKV  50000
#define CC   128
#define GG   8
#define SS   16
#define CSH  16

typedef short    bf16x8 __attribute__((ext_vector_type(8)));
typedef float    f32x4  __attribute__((ext_vector_type(4)));
typedef unsigned u32x4  __attribute__((ext_vector_type(4)));
typedef unsigned u32x2  __attribute__((ext_vector_type(2)));
typedef int      i32x4  __attribute__((ext_vector_type(4)));

__device__ __forceinline__ float bf_lo(unsigned u){ union{unsigned x; float f;} v; v.x = u << 16;        return v.f; }
__device__ __forceinline__ float bf_hi(unsigned u){ union{unsigned x; float f;} v; v.x = u & 0xffff0000u; return v.f; }
__device__ __forceinline__ unsigned short f2bfu(float f){
    __hip_bfloat16 h = __float2bfloat16(f);
    return *reinterpret_cast<unsigned short*>(&h);
}
__device__ __forceinline__ short f2bfs(float f){
    __hip_bfloat16 h = __float2bfloat16(f);
    return *reinterpret_cast<short*>(&h);
}

// Load 16 contiguous bf16 (32B, >=16B aligned) -> 16 fp32
__device__ __forceinline__ void load16bf(const __hip_bfloat16* ptr, float* o){
    const u32x4* p4 = reinterpret_cast<const u32x4*>(ptr);
    u32x4 a = p4[0]; u32x4 b = p4[1];
    o[0]=bf_lo(a[0]);  o[1]=bf_hi(a[0]);  o[2]=bf_lo(a[1]);  o[3]=bf_hi(a[1]);
    o[4]=bf_lo(a[2]);  o[5]=bf_hi(a[2]);  o[6]=bf_lo(a[3]);  o[7]=bf_hi(a[3]);
    o[8]=bf_lo(b[0]);  o[9]=bf_hi(b[0]);  o[10]=bf_lo(b[1]); o[11]=bf_hi(b[1]);
    o[12]=bf_lo(b[2]); o[13]=bf_hi(b[2]); o[14]=bf_lo(b[3]); o[15]=bf_hi(b[3]);
}

// Lazy dot: 16B of raw bf16 K against 8 fp32 q channels; accumulates sumk too.
__device__ __forceinline__ float dot8_lazy(const u32x4& a, const float* q8, float& sumk){
    float d = 0.f;
    #pragma unroll
    for (int j = 0; j < 4; ++j) {
        const float lo = bf_lo(a[j]), hi = bf_hi(a[j]);
        d    += lo * q8[2*j] + hi * q8[2*j+1];
        sumk += lo + hi;
    }
    return d;
}
// Weighted accumulate: 16B of raw bf16 V, acc8 += w * v
__device__ __forceinline__ void wacc8(const u32x4& a, float w, float* acc8){
    #pragma unroll
    for (int j = 0; j < 4; ++j) {
        acc8[2*j]   += w * bf_lo(a[j]);
        acc8[2*j+1] += w * bf_hi(a[j]);
    }
}

// Load 8 contiguous f32 (32B), convert to bf16x8 fragment
__device__ __forceinline__ bf16x8 cvt8(const float* p){
    const f32x4* q = reinterpret_cast<const f32x4*>(p);
    f32x4 u = q[0], v = q[1];
    bf16x8 r;
    r[0]=f2bfs(u[0]); r[1]=f2bfs(u[1]); r[2]=f2bfs(u[2]); r[3]=f2bfs(u[3]);
    r[4]=f2bfs(v[0]); r[5]=f2bfs(v[1]); r[6]=f2bfs(v[2]); r[7]=f2bfs(v[3]);
    return r;
}

// ---------------------------------------------------------------------------
// Kernel 1: Q/K/V projections, gridDim.y = 3 selects projection (0=Q,1=K,2=V).
// UNCHANGED (proven). K/V interleaved rows: [K 0..127 | V 128..255].
// ---------------------------------------------------------------------------
__global__ __launch_bounds__(256) void qkv_gemm(
    const float* __restrict__ x,
    const float* __restrict__ x2,
    const float* __restrict__ Wq, const float* __restrict__ Wk,
    const float* __restrict__ Wv,
    const float* __restrict__ bq, const float* __restrict__ bk,
    const float* __restrict__ bv,
    __hip_bfloat16* __restrict__ Qf,     // (NQ, 128)
    __hip_bfloat16* __restrict__ KVf)    // (NKV, 256) interleaved K|V
{
    __shared__ short lds16[16384];   // 32 KB

    const int tid  = threadIdx.x;
    const int wave = tid >> 6;
    const int lane = tid & 63;
    const int r    = lane & 15;
    const int kq   = lane >> 4;
    const int base = blockIdx.x * 128 + wave * 32;   // this wave's 32 rows
    const int proj = blockIdx.y;                     // 0=Q 1=K 2=V (uniform)

    const float* src  = (proj == 0) ? x  : x2;
    const float* W    = (proj == 0) ? Wq : (proj == 1 ? Wk : Wv);
    const float* bias = (proj == 0) ? bq : (proj == 1 ? bk : bv);
    short* dstb   = (proj == 0) ? (short*)Qf : (short*)KVf;
    const int dstride = (proj == 0) ? CC : 2 * CC;
    const int hoff    = (proj == 2) ? CC : 0;

    // load this wave's 32 source rows as B-fragments (2 m-tiles x 4 k-blocks)
    bf16x8 bfrag[2][4];
    #pragma unroll
    for (int mt = 0; mt < 2; ++mt) {
        int row = base + mt * 16 + r;
        if (row >= NQ) row = NQ - 1;           // clamp; stores guarded
        const float* xr = src + (size_t)row * CC + kq * 8;
        #pragma unroll
        for (int kb = 0; kb < 4; ++kb)
            bfrag[mt][kb] = cvt8(xr + kb * 32);
    }

    // stage one 128x128 f32 W into LDS (bf16, MFMA A-fragment order)
    #pragma unroll
    for (int i = 0; i < 8; ++i) {
        const int o   = i * 2048 + tid * 8;    // linear f32 offset in W
        const bf16x8 v = cvt8(W + o);
        const int row = o >> 7, col = o & 127;
        const int lchunk = (((row >> 4) * 4 + (col >> 5)) << 6)
                         + (((col >> 3) & 3) << 4) + (row & 15);
        *reinterpret_cast<bf16x8*>(&lds16[lchunk * 8]) = v;
    }
    __syncthreads();

    // 8 column tiles: LDS A-frags x register B-frags -> 2x f32x4 acc -> store
    #pragma unroll
    for (int t = 0; t < 8; ++t) {
        bf16x8 af[4];
        #pragma unroll
        for (int kb = 0; kb < 4; ++kb)
            af[kb] = *reinterpret_cast<const bf16x8*>(
                &lds16[(((t * 4 + kb) << 6) + lane) * 8]);

        f32x4 acc0 = {0.f,0.f,0.f,0.f}, acc1 = {0.f,0.f,0.f,0.f};
        #pragma unroll
        for (int kb = 0; kb < 4; ++kb) {
            acc0 = __builtin_amdgcn_mfma_f32_16x16x32_bf16(af[kb], bfrag[0][kb], acc0, 0, 0, 0);
            acc1 = __builtin_amdgcn_mfma_f32_16x16x32_bf16(af[kb], bfrag[1][kb], acc1, 0, 0, 0);
        }

        const f32x4 bi = *reinterpret_cast<const f32x4*>(bias + t * 16 + kq * 4);
        #pragma unroll
        for (int mt = 0; mt < 2; ++mt) {
            const int row = base + mt * 16 + r;
            if (row < NQ) {
                const f32x4 a = mt ? acc1 : acc0;
                u32x2 pk;
                pk[0] = (unsigned)f2bfu(a[0] + bi[0]) | ((unsigned)f2bfu(a[1] + bi[1]) << 16);
                pk[1] = (unsigned)f2bfu(a[2] + bi[2]) | ((unsigned)f2bfu(a[3] + bi[3]) << 16);
                *reinterpret_cast<u32x2*>(
                    dstb + (size_t)row * dstride + hoff + t * 16 + kq * 4) = pk;
            }
        }
    }
}

// ---------------------------------------------------------------------------
// Kernel 2: fused gather + positional MLP + grouped attention.
// Round-4 design (post-mortems r1: 156 VGPR blowup from unfenced full-unroll
// clustering; r2: preamble duplication from extra threads; r3: 140 VGPR from
// dual accumulators). Model: steady-state live set must stay low AND load
// clustering must be bounded EXPLICITLY.
//  - r0 thread layout: 1 thread per (n,g), 400K threads, preamble amortized
//    over all 16 neighbors.
//  - TWO-PHASE softmax (d[0..15] fully independent -> no serial rescale
//    chain), FULLY unrolled so every reg-array index is static (rule #20).
//  - sched_barrier(0) every 4 neighbors: scheduler can cluster at most one
//    window of loads (8 KV u32x4 + 12 p2 floats ~ 44 transient regs), giving
//    ~10-12 cache lines in flight per wave per window without r1's blowup.
//  - Lazy raw KV (u32x4 until consumed): 4 regs per 16B vs 8 unpacked floats.
//  - Phase 2: exact static max-tree + exp + pre-normalize (weights overwrite
//    d[]); phase 3 = pure weighted FMA sum, 8 transient regs/window.
// Kept: shifted exp (PE term ~250 overflows unshifted), logit algebra
// d = dot + prq*sumk + prk*sumq + 16*prk*prq. No barriers -> early-ret safe.
// ---------------------------------------------------------------------------
__global__ __launch_bounds__(256) void attn_kernel(
    const float* __restrict__ p,        // (NQ,3)
    const float* __restrict__ p2,       // (NKV,3)
    const int*   __restrict__ idx,      // (NQ,SS)
    const float* __restrict__ W1,       // (3,3)
    const float* __restrict__ b1,       // (3,)
    const float* __restrict__ bn_gamma,
    const float* __restrict__ bn_beta,
    const float* __restrict__ bn_mean,
    const float* __restrict__ bn_var,
    const float* __restrict__ W2,       // (16,3)
    const float* __restrict__ b2,       // (16,)
    const __hip_bfloat16* __restrict__ Qf,   // (NQ,128) bf16
    const __hip_bfloat16* __restrict__ KVf,  // (NKV,256) bf16 interleaved
    float* __restrict__ out)            // (NQ,CC) f32
{
    const int tid = blockIdx.x * 256 + threadIdx.x;
    if (tid >= NQ * GG) return;
    const int n = tid >> 3;
    const int g = tid & 7;

    // --- fold BN into the 3x3 conv (uniform) ---
    float fw1[3][3], fb1[3];
    #pragma unroll
    for (int j = 0; j < 3; ++j) {
        const float sc = bn_gamma[j] * rsqrtf(bn_var[j] + 1e-5f);
        #pragma unroll
        for (int k = 0; k < 3; ++k) fw1[j][k] = W1[j*3 + k] * sc;
        fb1[j] = (b1[j] - bn_mean[j]) * sc + bn_beta[j];
    }
    const float w2q0 = W2[g*3+0],     w2q1 = W2[g*3+1],     w2q2 = W2[g*3+2];
    const float w2k0 = W2[(g+8)*3+0], w2k1 = W2[(g+8)*3+1], w2k2 = W2[(g+8)*3+2];
    const float b2q = b2[g], b2k = b2[g+8];

    const float px = p[(size_t)n*3+0];
    const float py = p[(size_t)n*3+1];
    const float pz = p[(size_t)n*3+2];

    // --- neighbor indices (16 ints = 64B aligned) ---
    int nbr[SS];
    {
        const i32x4* ip = reinterpret_cast<const i32x4*>(idx + (size_t)n * SS);
        i32x4 i0 = ip[0], i1 = ip[1], i2 = ip[2], i3 = ip[3];
        nbr[0]=i0[0]; nbr[1]=i0[1]; nbr[2]=i0[2]; nbr[3]=i0[3];
        nbr[4]=i1[0]; nbr[5]=i1[1]; nbr[6]=i1[2]; nbr[7]=i1[3];
        nbr[8]=i2[0]; nbr[9]=i2[1]; nbr[10]=i2[2]; nbr[11]=i2[3];
        nbr[12]=i3[0]; nbr[13]=i3[1]; nbr[14]=i3[2]; nbr[15]=i3[3];
    }

    // --- query fragment for this group ---
    float q[CSH];
    load16bf(Qf + (size_t)n * CC + g * CSH, q);
    float sumq = 0.f;
    #pragma unroll
    for (int c = 0; c < CSH; ++c) sumq += q[c];

    // --- phase 1: logits, fenced windows of 4 (bounded load clustering) ---
    float d[SS];
    #pragma unroll
    for (int wnd = 0; wnd < 4; ++wnd) {
        u32x4 k0[4], k1[4];
        float rx[4], ry[4], rz[4];
        // batch-issue this window's gathers (8 KV 16B + 12 p2 floats)
        #pragma unroll
        for (int j = 0; j < 4; ++j) {
            const int i = nbr[wnd*4 + j];
            const u32x4* kv = reinterpret_cast<const u32x4*>(
                KVf + (size_t)i * (2*CC) + g * CSH);
            k0[j] = kv[0]; k1[j] = kv[1];
            rx[j] = p2[(size_t)i*3+0] - px;
            ry[j] = p2[(size_t)i*3+1] - py;
            rz[j] = p2[(size_t)i*3+2] - pz;
        }
        // consume
        #pragma unroll
        for (int j = 0; j < 4; ++j) {
            const float h0 = fmaxf(fw1[0][0]*rx[j] + fw1[0][1]*ry[j] + fw1[0][2]*rz[j] + fb1[0], 0.f);
            const float h1 = fmaxf(fw1[1][0]*rx[j] + fw1[1][1]*ry[j] + fw1[1][2]*rz[j] + fb1[1], 0.f);
            const float h2 = fmaxf(fw1[2][0]*rx[j] + fw1[2][1]*ry[j] + fw1[2][2]*rz[j] + fb1[2], 0.f);
            const float prq = w2q0*h0 + w2q1*h1 + w2q2*h2 + b2q;
            const float prk = w2k0*h0 + w2k1*h1 + w2k2*h2 + b2k;
            float sumk = 0.f;
            const float dot = dot8_lazy(k0[j], q, sumk) + dot8_lazy(k1[j], q + 8, sumk);
            d[wnd*4 + j] = (dot + prq*sumk + prk*sumq + 16.f*prk*prq) * 0.25f;
        }
        __builtin_amdgcn_sched_barrier(0);   // bound clustering to one window
    }

    // --- phase 2: exact softmax, static tree, pre-normalized weights ---
    float m01 = fmaxf(d[0], d[1]),   m23 = fmaxf(d[2], d[3]);
    float m45 = fmaxf(d[4], d[5]),   m67 = fmaxf(d[6], d[7]);
    float m89 = fmaxf(d[8], d[9]),   mab = fmaxf(d[10], d[11]);
    float mcd = fmaxf(d[12], d[13]), mef = fmaxf(d[14], d[15]);
    const float M = fmaxf(fmaxf(fmaxf(m01, m23), fmaxf(m45, m67)),
                          fmaxf(fmaxf(m89, mab), fmaxf(mcd, mef)));
    float sum = 0.f;
    #pragma unroll
    for (int s = 0; s < SS; ++s) { d[s] = __expf(d[s] - M); sum += d[s]; }
    const float inv = 1.f / sum;
    #pragma unroll
    for (int s = 0; s < SS; ++s) d[s] *= inv;    // d[] now holds weights

    // --- phase 3: V gathers, fenced windows of 4, pure weighted FMA ---
    float acc[CSH];
    #pragma unroll
    for (int c = 0; c < CSH; ++c) acc[c] = 0.f;
    #pragma unroll
    for (int wnd = 0; wnd < 4; ++wnd) {
        u32x4 v0[4], v1[4];
        #pragma unroll
        for (int j = 0; j < 4; ++j) {
            const int i = nbr[wnd*4 + j];
            const u32x4* kv = reinterpret_cast<const u32x4*>(
                KVf + (size_t)i * (2*CC) + CC + g * CSH);
            v0[j] = kv[0]; v1[j] = kv[1];
        }
        #pragma unroll
        for (int j = 0; j < 4; ++j) {
            wacc8(v0[j], d[wnd*4 + j], acc);
            wacc8(v1[j], d[wnd*4 + j], acc + 8);
        }
        __builtin_amdgcn_sched_barrier(0);
    }

    // --- store 16 f32 (64B; 8 lanes of one n cover 512B contiguous) ---
    f32x4* op = reinterpret_cast<f32x4*>(out + (size_t)n * CC + g * CSH);
    f32x4 o0 = {acc[0],  acc[1],  acc[2],  acc[3]};
    f32x4 o1 = {acc[4],  acc[5],  acc[6],  acc[7]};
    f32x4 o2 = {acc[8],  acc[9],  acc[10], acc[11]};
    f32x4 o3 = {acc[12], acc[13], acc[14], acc[15]};
    op[0] = o0; op[1] = o1; op[2] = o2; op[3] = o3;
}

// ---------------------------------------------------------------------------
extern "C" void kernel_launch(void* const* d_in, const int* in_sizes, int n_in,
                              void* d_out, int out_size, void* d_ws, size_t ws_size,
                              hipStream_t stream) {
    const float* p   = (const float*)d_in[0];
    const float* x   = (const float*)d_in[1];
    const float* p2  = (const float*)d_in[2];
    const float* x2  = (const float*)d_in[3];
    const int*   idx = (const int*)d_in[4];
    const float* Wq  = (const float*)d_in[5];
    const float* bq  = (const float*)d_in[6];
    const float* Wk  = (const float*)d_in[7];
    const float* bk  = (const float*)d_in[8];
    const float* Wv  = (const float*)d_in[9];
    const float* bv  = (const float*)d_in[10];
    const float* W1  = (const float*)d_in[11];
    const float* b1  = (const float*)d_in[12];
    const float* bng = (const float*)d_in[13];
    const float* bnb = (const float*)d_in[14];
    const float* bnm = (const float*)d_in[15];
    const float* bnv = (const float*)d_in[16];
    const float* W2  = (const float*)d_in[17];
    const float* b2  = (const float*)d_in[18];
    float* out = (float*)d_out;

    // workspace: Qf (12.8 MB) | KVf interleaved (25.6 MB)
    __hip_bfloat16* Qf  = (__hip_bfloat16*)d_ws;
    __hip_bfloat16* KVf = Qf + (size_t)NQ * CC;

    // 50000 rows / 128 rows-per-block = 391 blocks; y-dim = projection (Q,K,V)
    qkv_gemm<<<dim3(391, 3), 256, 0, stream>>>(
        x, x2, Wq, Wk, Wv, bq, bk, bv, Qf, KVf);

    // 50000 * 8 groups = 400000 threads -> 1563 blocks (tail returns early)
    attn_kernel<<<(NQ * GG + 255) / 256, 256, 0, stream>>>(
        p, p2, idx, W1, b1, bng, bnb, bnm, bnv, W2, b2, Qf, KVf, out);
}

// Round 7
// 211.056 us; speedup vs baseline: 1.2700x; 1.0578x over previous
//
#include <hip/hip_runtime.h>
#include <hip/hip_bf16.h>

#define NQ   50000
#define NKV  50000
#define CC   128
#define GG   8
#define SS   16
#define CSH  16

typedef short    bf16x8 __attribute__((ext_vector_type(8)));
typedef float    f32x4  __attribute__((ext_vector_type(4)));
typedef unsigned u32x4  __attribute__((ext_vector_type(4)));
typedef unsigned u32x2  __attribute__((ext_vector_type(2)));
typedef int      i32x4  __attribute__((ext_vector_type(4)));

__device__ __forceinline__ float bf_lo(unsigned u){ union{unsigned x; float f;} v; v.x = u << 16;        return v.f; }
__device__ __forceinline__ float bf_hi(unsigned u){ union{unsigned x; float f;} v; v.x = u & 0xffff0000u; return v.f; }
__device__ __forceinline__ unsigned short f2bfu(float f){
    __hip_bfloat16 h = __float2bfloat16(f);
    return *reinterpret_cast<unsigned short*>(&h);
}
__device__ __forceinline__ short f2bfs(float f){
    __hip_bfloat16 h = __float2bfloat16(f);
    return *reinterpret_cast<short*>(&h);
}

// Lazy dot: 16B raw bf16 K x 16B raw bf16 Q (8 channels); accumulates sumk.
__device__ __forceinline__ float dot8_qraw(const u32x4& k, const u32x4& qr, float& sumk){
    float d = 0.f;
    #pragma unroll
    for (int j = 0; j < 4; ++j) {
        const float klo = bf_lo(k[j]), khi = bf_hi(k[j]);
        d    += klo * bf_lo(qr[j]) + khi * bf_hi(qr[j]);
        sumk += klo + khi;
    }
    return d;
}
// Online accumulate: 16B raw bf16 V into 8 fp32 acc channels with rescale.
__device__ __forceinline__ void acc8_lazy(const u32x4& a, float corr, float w, float* acc8){
    #pragma unroll
    for (int j = 0; j < 4; ++j) {
        acc8[2*j]   = acc8[2*j]  * corr + w * bf_lo(a[j]);
        acc8[2*j+1] = acc8[2*j+1]* corr + w * bf_hi(a[j]);
    }
}

// Load 8 contiguous f32 (32B), convert to bf16x8 fragment
__device__ __forceinline__ bf16x8 cvt8(const float* p){
    const f32x4* q = reinterpret_cast<const f32x4*>(p);
    f32x4 u = q[0], v = q[1];
    bf16x8 r;
    r[0]=f2bfs(u[0]); r[1]=f2bfs(u[1]); r[2]=f2bfs(u[2]); r[3]=f2bfs(u[3]);
    r[4]=f2bfs(v[0]); r[5]=f2bfs(v[1]); r[6]=f2bfs(v[2]); r[7]=f2bfs(v[3]);
    return r;
}

// ---------------------------------------------------------------------------
// Kernel 1: Q/K/V projections, gridDim.y = 3 selects projection (0=Q,1=K,2=V).
// UNCHANGED (proven best variant). K/V interleaved rows: [K 0..127|V 128..255].
// ---------------------------------------------------------------------------
__global__ __launch_bounds__(256) void qkv_gemm(
    const float* __restrict__ x,
    const float* __restrict__ x2,
    const float* __restrict__ Wq, const float* __restrict__ Wk,
    const float* __restrict__ Wv,
    const float* __restrict__ bq, const float* __restrict__ bk,
    const float* __restrict__ bv,
    __hip_bfloat16* __restrict__ Qf,     // (NQ, 128)
    __hip_bfloat16* __restrict__ KVf)    // (NKV, 256) interleaved K|V
{
    __shared__ short lds16[16384];   // 32 KB

    const int tid  = threadIdx.x;
    const int wave = tid >> 6;
    const int lane = tid & 63;
    const int r    = lane & 15;
    const int kq   = lane >> 4;
    const int base = blockIdx.x * 128 + wave * 32;   // this wave's 32 rows
    const int proj = blockIdx.y;                     // 0=Q 1=K 2=V (uniform)

    const float* src  = (proj == 0) ? x  : x2;
    const float* W    = (proj == 0) ? Wq : (proj == 1 ? Wk : Wv);
    const float* bias = (proj == 0) ? bq : (proj == 1 ? bk : bv);
    short* dstb   = (proj == 0) ? (short*)Qf : (short*)KVf;
    const int dstride = (proj == 0) ? CC : 2 * CC;
    const int hoff    = (proj == 2) ? CC : 0;

    // load this wave's 32 source rows as B-fragments (2 m-tiles x 4 k-blocks)
    bf16x8 bfrag[2][4];
    #pragma unroll
    for (int mt = 0; mt < 2; ++mt) {
        int row = base + mt * 16 + r;
        if (row >= NQ) row = NQ - 1;           // clamp; stores guarded
        const float* xr = src + (size_t)row * CC + kq * 8;
        #pragma unroll
        for (int kb = 0; kb < 4; ++kb)
            bfrag[mt][kb] = cvt8(xr + kb * 32);
    }

    // stage one 128x128 f32 W into LDS (bf16, MFMA A-fragment order)
    #pragma unroll
    for (int i = 0; i < 8; ++i) {
        const int o   = i * 2048 + tid * 8;    // linear f32 offset in W
        const bf16x8 v = cvt8(W + o);
        const int row = o >> 7, col = o & 127;
        const int lchunk = (((row >> 4) * 4 + (col >> 5)) << 6)
                         + (((col >> 3) & 3) << 4) + (row & 15);
        *reinterpret_cast<bf16x8*>(&lds16[lchunk * 8]) = v;
    }
    __syncthreads();

    // 8 column tiles: LDS A-frags x register B-frags -> 2x f32x4 acc -> store
    #pragma unroll
    for (int t = 0; t < 8; ++t) {
        bf16x8 af[4];
        #pragma unroll
        for (int kb = 0; kb < 4; ++kb)
            af[kb] = *reinterpret_cast<const bf16x8*>(
                &lds16[(((t * 4 + kb) << 6) + lane) * 8]);

        f32x4 acc0 = {0.f,0.f,0.f,0.f}, acc1 = {0.f,0.f,0.f,0.f};
        #pragma unroll
        for (int kb = 0; kb < 4; ++kb) {
            acc0 = __builtin_amdgcn_mfma_f32_16x16x32_bf16(af[kb], bfrag[0][kb], acc0, 0, 0, 0);
            acc1 = __builtin_amdgcn_mfma_f32_16x16x32_bf16(af[kb], bfrag[1][kb], acc1, 0, 0, 0);
        }

        const f32x4 bi = *reinterpret_cast<const f32x4*>(bias + t * 16 + kq * 4);
        #pragma unroll
        for (int mt = 0; mt < 2; ++mt) {
            const int row = base + mt * 16 + r;
            if (row < NQ) {
                const f32x4 a = mt ? acc1 : acc0;
                u32x2 pk;
                pk[0] = (unsigned)f2bfu(a[0] + bi[0]) | ((unsigned)f2bfu(a[1] + bi[1]) << 16);
                pk[1] = (unsigned)f2bfu(a[2] + bi[2]) | ((unsigned)f2bfu(a[3] + bi[3]) << 16);
                *reinterpret_cast<u32x2*>(
                    dstb + (size_t)row * dstride + hoff + t * 16 + kq * 4) = pk;
            }
        }
    }
}

// ---------------------------------------------------------------------------
// Kernel 2: fused gather + positional MLP + grouped attention.
// Round-7 = round-5 design, re-submitted again (r5: container failure, r6:
// GPU acquisition timeout -- no measurement signal either round). Law from
// r1/r3/r4: dependency-free gather structures let the compiler hoist
// everything -> 140-192 VGPR -> <10% occupancy. The online softmax chain
// (r0, 56 VGPR) anchors the scheduler. Keep the chain; add MLP via an
// explicit 2-slot software-pipeline ring:
//  - named slot registers (A/B), loop ROLLED (#pragma unroll 1) so the
//    backedge bounds hoisting; slot s+2's loads issue right after slot s is
//    consumed -> loads lead use by one full body (~400-500 cyc).
//  - register diet: no nbr[16] (idx row re-read per use, L1-hot), q RAW
//    (2x u32x4), slots hold raw u32x4 K/V.
// Wrap clamp min(s,15): end-of-ring prefetches re-read live slots (L1-hot,
// results dead) instead of ring slots 0/1 -- zero semantic change.
// Target ~95 VGPR -> 5 waves/SIMD. Ceiling experiment: hbm_gbps pinned at
// ~3.5 TB/s despite deeper pipeline => random-gather fabric ceiling.
// Kept: shifted exp (PE term ~250 overflows unshifted), logit algebra
// d = dot + prq*sumk + prk*sumq + 16*prk*prq. No barriers -> early-ret safe.
// ---------------------------------------------------------------------------
__global__ __launch_bounds__(256) void attn_kernel(
    const float* __restrict__ p,        // (NQ,3)
    const float* __restrict__ p2,       // (NKV,3)
    const int*   __restrict__ idx,      // (NQ,SS)
    const float* __restrict__ W1,       // (3,3)
    const float* __restrict__ b1,       // (3,)
    const float* __restrict__ bn_gamma,
    const float* __restrict__ bn_beta,
    const float* __restrict__ bn_mean,
    const float* __restrict__ bn_var,
    const float* __restrict__ W2,       // (16,3)
    const float* __restrict__ b2,       // (16,)
    const __hip_bfloat16* __restrict__ Qf,   // (NQ,128) bf16
    const __hip_bfloat16* __restrict__ KVf,  // (NKV,256) bf16 interleaved
    float* __restrict__ out)            // (NQ,CC) f32
{
    const int tid = blockIdx.x * 256 + threadIdx.x;
    if (tid >= NQ * GG) return;
    const int n = tid >> 3;
    const int g = tid & 7;

    // --- fold BN into the 3x3 conv (uniform) ---
    float fw1[3][3], fb1[3];
    #pragma unroll
    for (int j = 0; j < 3; ++j) {
        const float sc = bn_gamma[j] * rsqrtf(bn_var[j] + 1e-5f);
        #pragma unroll
        for (int k = 0; k < 3; ++k) fw1[j][k] = W1[j*3 + k] * sc;
        fb1[j] = (b1[j] - bn_mean[j]) * sc + bn_beta[j];
    }
    const float w2q0 = W2[g*3+0],     w2q1 = W2[g*3+1],     w2q2 = W2[g*3+2];
    const float w2k0 = W2[(g+8)*3+0], w2k1 = W2[(g+8)*3+1], w2k2 = W2[(g+8)*3+2];
    const float b2q = b2[g], b2k = b2[g+8];

    const float px = p[(size_t)n*3+0];
    const float py = p[(size_t)n*3+1];
    const float pz = p[(size_t)n*3+2];

    const int* __restrict__ idxr = idx + (size_t)n * SS;  // one 64B line, L1-hot

    // --- query fragment: RAW bf16 (8 regs), lazy-unpacked in dot ---
    u32x4 qr0, qr1;
    {
        const u32x4* qp = reinterpret_cast<const u32x4*>(Qf + (size_t)n * CC + g * CSH);
        qr0 = qp[0]; qr1 = qp[1];
    }
    float sumq = 0.f;
    #pragma unroll
    for (int j = 0; j < 4; ++j) sumq += bf_lo(qr0[j]) + bf_hi(qr0[j])
                                      + bf_lo(qr1[j]) + bf_hi(qr1[j]);

    // --- 2-slot prefetch ring ---
    u32x4 kA0, kA1, vA0, vA1; float rAx, rAy, rAz;
    u32x4 kB0, kB1, vB0, vB1; float rBx, rBy, rBz;

    auto PF = [&](int s, u32x4& k0, u32x4& k1, u32x4& v0, u32x4& v1,
                  float& rx, float& ry, float& rz) {
        const int i = idxr[s];
        const u32x4* kv = reinterpret_cast<const u32x4*>(
            KVf + (size_t)i * (2 * CC) + g * CSH);
        k0 = kv[0]; k1 = kv[1];          // K slice (32B)
        v0 = kv[16]; v1 = kv[17];        // V slice at +256B
        rx = p2[(size_t)i*3+0] - px;
        ry = p2[(size_t)i*3+1] - py;
        rz = p2[(size_t)i*3+2] - pz;
    };

    float acc[CSH];
    #pragma unroll
    for (int c = 0; c < CSH; ++c) acc[c] = 0.f;
    float sum = 0.f;
    float m = -3.0e38f;

    auto CONSUME = [&](const u32x4& k0, const u32x4& k1,
                       const u32x4& v0, const u32x4& v1,
                       float rx, float ry, float rz) {
        const float h0 = fmaxf(fw1[0][0]*rx + fw1[0][1]*ry + fw1[0][2]*rz + fb1[0], 0.f);
        const float h1 = fmaxf(fw1[1][0]*rx + fw1[1][1]*ry + fw1[1][2]*rz + fb1[1], 0.f);
        const float h2 = fmaxf(fw1[2][0]*rx + fw1[2][1]*ry + fw1[2][2]*rz + fb1[2], 0.f);
        const float prq = w2q0*h0 + w2q1*h1 + w2q2*h2 + b2q;
        const float prk = w2k0*h0 + w2k1*h1 + w2k2*h2 + b2k;

        float sumk = 0.f;
        const float dot = dot8_qraw(k0, qr0, sumk) + dot8_qraw(k1, qr1, sumk);
        const float d = (dot + prq*sumk + prk*sumq + 16.f*prk*prq) * 0.25f;

        const float mnew = fmaxf(m, d);
        const float corr = __expf(m - mnew);   // 1.0 when max unchanged
        const float w    = __expf(d - mnew);
        sum = sum * corr + w;
        acc8_lazy(v0, corr, w, acc);
        acc8_lazy(v1, corr, w, acc + 8);
        m = mnew;
    };

    // prologue: fill both slots
    PF(0, kA0, kA1, vA0, vA1, rAx, rAy, rAz);
    PF(1, kB0, kB1, vB0, vB1, rBx, rBy, rBz);

    // steady state: consume slot, immediately refill with s+2 (clamped at the
    // end: final refills re-read live slots, results dead).
    #pragma unroll 1
    for (int it = 0; it < 8; ++it) {
        const int sA = (2*it + 2 < SS) ? (2*it + 2) : (SS - 1);
        const int sB = (2*it + 3 < SS) ? (2*it + 3) : (SS - 1);
        CONSUME(kA0, kA1, vA0, vA1, rAx, rAy, rAz);
        PF(sA, kA0, kA1, vA0, vA1, rAx, rAy, rAz);
        CONSUME(kB0, kB1, vB0, vB1, rBx, rBy, rBz);
        PF(sB, kB0, kB1, vB0, vB1, rBx, rBy, rBz);
    }

    const float inv = 1.f / sum;

    // --- store 16 f32 (64B; 8 lanes of one n cover 512B contiguous) ---
    f32x4* op = reinterpret_cast<f32x4*>(out + (size_t)n * CC + g * CSH);
    f32x4 o0 = {acc[0]*inv,  acc[1]*inv,  acc[2]*inv,  acc[3]*inv};
    f32x4 o1 = {acc[4]*inv,  acc[5]*inv,  acc[6]*inv,  acc[7]*inv};
    f32x4 o2 = {acc[8]*inv,  acc[9]*inv,  acc[10]*inv, acc[11]*inv};
    f32x4 o3 = {acc[12]*inv, acc[13]*inv, acc[14]*inv, acc[15]*inv};
    op[0] = o0; op[1] = o1; op[2] = o2; op[3] = o3;
}

// ---------------------------------------------------------------------------
extern "C" void kernel_launch(void* const* d_in, const int* in_sizes, int n_in,
                              void* d_out, int out_size, void* d_ws, size_t ws_size,
                              hipStream_t stream) {
    const float* p   = (const float*)d_in[0];
    const float* x   = (const float*)d_in[1];
    const float* p2  = (const float*)d_in[2];
    const float* x2  = (const float*)d_in[3];
    const int*   idx = (const int*)d_in[4];
    const float* Wq  = (const float*)d_in[5];
    const float* bq  = (const float*)d_in[6];
    const float* Wk  = (const float*)d_in[7];
    const float* bk  = (const float*)d_in[8];
    const float* Wv  = (const float*)d_in[9];
    const float* bv  = (const float*)d_in[10];
    const float* W1  = (const float*)d_in[11];
    const float* b1  = (const float*)d_in[12];
    const float* bng = (const float*)d_in[13];
    const float* bnb = (const float*)d_in[14];
    const float* bnm = (const float*)d_in[15];
    const float* bnv = (const float*)d_in[16];
    const float* W2  = (const float*)d_in[17];
    const float* b2  = (const float*)d_in[18];
    float* out = (float*)d_out;

    // workspace: Qf (12.8 MB) | KVf interleaved (25.6 MB)
    __hip_bfloat16* Qf  = (__hip_bfloat16*)d_ws;
    __hip_bfloat16* KVf = Qf + (size_t)NQ * CC;

    // 50000 rows / 128 rows-per-block = 391 blocks; y-dim = projection (Q,K,V)
    qkv_gemm<<<dim3(391, 3), 256, 0, stream>>>(
        x, x2, Wq, Wk, Wv, bq, bk, bv, Qf, KVf);

    // 50000 * 8 groups = 400000 threads -> 1563 blocks (tail returns early)
    attn_kernel<<<(NQ * GG + 255) / 256, 256, 0, stream>>>(
        p, p2, idx, W1, b1, bng, bnb, bnm, bnv, W2, b2, Qf, KVf, out);
}

// Round 8
// 211.037 us; speedup vs baseline: 1.2701x; 1.0001x over previous
//
#include <hip/hip_runtime.h>
#include <hip/hip_bf16.h>

#define NQ   50000
#define NKV  50000
#define CC   128
#define GG   8
#define SS   16
#define CSH  16

typedef short    bf16x8 __attribute__((ext_vector_type(8)));
typedef float    f32x4  __attribute__((ext_vector_type(4)));
typedef unsigned u32x4  __attribute__((ext_vector_type(4)));
typedef unsigned u32x2  __attribute__((ext_vector_type(2)));
typedef int      i32x4  __attribute__((ext_vector_type(4)));

__device__ __forceinline__ float bf_lo(unsigned u){ union{unsigned x; float f;} v; v.x = u << 16;        return v.f; }
__device__ __forceinline__ float bf_hi(unsigned u){ union{unsigned x; float f;} v; v.x = u & 0xffff0000u; return v.f; }
__device__ __forceinline__ unsigned short f2bfu(float f){
    __hip_bfloat16 h = __float2bfloat16(f);
    return *reinterpret_cast<unsigned short*>(&h);
}
__device__ __forceinline__ short f2bfs(float f){
    __hip_bfloat16 h = __float2bfloat16(f);
    return *reinterpret_cast<short*>(&h);
}

// Load 16 contiguous bf16 (32B, >=16B aligned) -> 16 fp32
__device__ __forceinline__ void load16bf(const __hip_bfloat16* ptr, float* o){
    const u32x4* p4 = reinterpret_cast<const u32x4*>(ptr);
    u32x4 a = p4[0]; u32x4 b = p4[1];
    o[0]=bf_lo(a[0]);  o[1]=bf_hi(a[0]);  o[2]=bf_lo(a[1]);  o[3]=bf_hi(a[1]);
    o[4]=bf_lo(a[2]);  o[5]=bf_hi(a[2]);  o[6]=bf_lo(a[3]);  o[7]=bf_hi(a[3]);
    o[8]=bf_lo(b[0]);  o[9]=bf_hi(b[0]);  o[10]=bf_lo(b[1]); o[11]=bf_hi(b[1]);
    o[12]=bf_lo(b[2]); o[13]=bf_hi(b[2]); o[14]=bf_lo(b[3]); o[15]=bf_hi(b[3]);
}

// Load 8 contiguous f32 (32B), convert to bf16x8 fragment
__device__ __forceinline__ bf16x8 cvt8(const float* p){
    const f32x4* q = reinterpret_cast<const f32x4*>(p);
    f32x4 u = q[0], v = q[1];
    bf16x8 r;
    r[0]=f2bfs(u[0]); r[1]=f2bfs(u[1]); r[2]=f2bfs(u[2]); r[3]=f2bfs(u[3]);
    r[4]=f2bfs(v[0]); r[5]=f2bfs(v[1]); r[6]=f2bfs(v[2]); r[7]=f2bfs(v[3]);
    return r;
}

// ---------------------------------------------------------------------------
// Kernel 0 (NEW, round-8): one-time W pre-permutation. Converts Wq/Wk/Wv
// (128x128 f32) to bf16 stored in the EXACT linear order qkv_gemm's LDS
// wants (the lchunk MFMA-A-fragment layout). qkv staging then needs zero
// VALU (global_load_lds straight copy) and half the W bytes.
// Forward map (from old staging): for f32 offset o: row=o>>7, col=o&127,
//   chunk = ((row>>4)*4+(col>>5))*64 + ((col>>3)&3)*16 + (row&15), e=col&7,
//   linear bf16 index L = chunk*8 + e.
// Inverse (used here): q=chunk>>6, rem=chunk&63, c3=rem>>4, r15=rem&15,
//   row = ((q>>2)<<4)|r15, colb = ((q&3)<<5)|(c3<<3).
// Verified example: row=17,col=40 -> chunk 337 -> inverse gives (17,40). OK.
// 3 blocks x 256 threads, 8 chunks/thread; ~3-5 us.
// ---------------------------------------------------------------------------
__global__ __launch_bounds__(256) void wprep(
    const float* __restrict__ Wq, const float* __restrict__ Wk,
    const float* __restrict__ Wv,
    __hip_bfloat16* __restrict__ Wp)     // (3, 16384) bf16, lchunk order
{
    const float* W = (blockIdx.x == 0) ? Wq : (blockIdx.x == 1) ? Wk : Wv;
    __hip_bfloat16* o = Wp + blockIdx.x * 16384;
    #pragma unroll
    for (int k = 0; k < 8; ++k) {
        const int chunk = k * 256 + threadIdx.x;          // 0..2047
        const int q   = chunk >> 6;
        const int rem = chunk & 63;
        const int c3  = rem >> 4, r15 = rem & 15;
        const int row  = ((q >> 2) << 4) | r15;
        const int colb = ((q & 3) << 5) | (c3 << 3);
        const bf16x8 v = cvt8(W + row * 128 + colb);      // 8 consecutive cols
        *reinterpret_cast<bf16x8*>(o + chunk * 8) = v;
    }
}

// ---------------------------------------------------------------------------
// Kernel 1: Q/K/V projections, gridDim.y = 3 selects projection (0=Q,1=K,2=V).
// Round-8 change: W staging via 8x global_load_lds(16B) from the pre-permuted
// bf16 Wp -- removes 64 v_cvt + 8 ds_write_b128 per thread and halves W
// fetch bytes. LDS dest is wave-uniform base + lane*16 (HW rule), so the
// per-lane global pointer carries the lane*16B term and LDS layout stays
// linear = lchunk order. __syncthreads() drains the DMA (vmcnt 0 before
// barrier, compiler-emitted). Everything else unchanged (proven).
// K/V interleaved rows: [K 0..127 | V 128..255].
// ---------------------------------------------------------------------------
__global__ __launch_bounds__(256) void qkv_gemm(
    const float* __restrict__ x,
    const float* __restrict__ x2,
    const __hip_bfloat16* __restrict__ Wp,   // (3,16384) pre-permuted bf16
    const float* __restrict__ bq, const float* __restrict__ bk,
    const float* __restrict__ bv,
    __hip_bfloat16* __restrict__ Qf,     // (NQ, 128)
    __hip_bfloat16* __restrict__ KVf)    // (NKV, 256) interleaved K|V
{
    __shared__ short lds16[16384];   // 32 KB

    const int tid  = threadIdx.x;
    const int wave = tid >> 6;
    const int lane = tid & 63;
    const int r    = lane & 15;
    const int kq   = lane >> 4;
    const int base = blockIdx.x * 128 + wave * 32;   // this wave's 32 rows
    const int proj = blockIdx.y;                     // 0=Q 1=K 2=V (uniform)

    const float* src  = (proj == 0) ? x  : x2;
    const float* bias = (proj == 0) ? bq : (proj == 1 ? bk : bv);
    short* dstb   = (proj == 0) ? (short*)Qf : (short*)KVf;
    const int dstride = (proj == 0) ? CC : 2 * CC;
    const int hoff    = (proj == 2) ? CC : 0;

    // stage this projection's pre-permuted W: 8 x 16B DMA per thread, no VALU
    {
        const __hip_bfloat16* Wsrc = Wp + proj * 16384;
        #pragma unroll
        for (int i = 0; i < 8; ++i) {
            const int el = i * 2048 + wave * 512;        // wave-uniform element base
            __builtin_amdgcn_global_load_lds(
                (const __attribute__((address_space(1))) void*)(Wsrc + el + lane * 8),
                (__attribute__((address_space(3))) void*)(&lds16[el]),
                16, 0, 0);
        }
    }

    // load this wave's 32 source rows as B-fragments (2 m-tiles x 4 k-blocks)
    bf16x8 bfrag[2][4];
    #pragma unroll
    for (int mt = 0; mt < 2; ++mt) {
        int row = base + mt * 16 + r;
        if (row >= NQ) row = NQ - 1;           // clamp; stores guarded
        const float* xr = src + (size_t)row * CC + kq * 8;
        #pragma unroll
        for (int kb = 0; kb < 4; ++kb)
            bfrag[mt][kb] = cvt8(xr + kb * 32);
    }
    __syncthreads();                            // drains global_load_lds too

    // 8 column tiles: LDS A-frags x register B-frags -> 2x f32x4 acc -> store
    #pragma unroll
    for (int t = 0; t < 8; ++t) {
        bf16x8 af[4];
        #pragma unroll
        for (int kb = 0; kb < 4; ++kb)
            af[kb] = *reinterpret_cast<const bf16x8*>(
                &lds16[(((t * 4 + kb) << 6) + lane) * 8]);

        f32x4 acc0 = {0.f,0.f,0.f,0.f}, acc1 = {0.f,0.f,0.f,0.f};
        #pragma unroll
        for (int kb = 0; kb < 4; ++kb) {
            acc0 = __builtin_amdgcn_mfma_f32_16x16x32_bf16(af[kb], bfrag[0][kb], acc0, 0, 0, 0);
            acc1 = __builtin_amdgcn_mfma_f32_16x16x32_bf16(af[kb], bfrag[1][kb], acc1, 0, 0, 0);
        }

        const f32x4 bi = *reinterpret_cast<const f32x4*>(bias + t * 16 + kq * 4);
        #pragma unroll
        for (int mt = 0; mt < 2; ++mt) {
            const int row = base + mt * 16 + r;
            if (row < NQ) {
                const f32x4 a = mt ? acc1 : acc0;
                u32x2 pk;
                pk[0] = (unsigned)f2bfu(a[0] + bi[0]) | ((unsigned)f2bfu(a[1] + bi[1]) << 16);
                pk[1] = (unsigned)f2bfu(a[2] + bi[2]) | ((unsigned)f2bfu(a[3] + bi[3]) << 16);
                *reinterpret_cast<u32x2*>(
                    dstb + (size_t)row * dstride + hoff + t * 16 + kq * 4) = pk;
            }
        }
    }
}

// ---------------------------------------------------------------------------
// Kernel 2: fused gather + positional MLP + grouped attention -- REVERTED to
// the round-0 online-softmax kernel (best measured: ~64 us, VGPR 56).
// Round-7 closed the ceiling experiment: five structures (online, split-S,
// 2-slot ring, two ILP variants) all pin at 3.1-3.5 TB/s fabric on the
// random 512B-granule gather; duration is insensitive to MLP depth and
// occupancy (26-36%). attn is at the effective random-gather fabric ceiling;
// demand traffic is already minimal (8 lanes/n coalesce the full KV row).
// Kept: shifted exp (PE term ~250 overflows unshifted), online max chain
// (the only structure that keeps VGPR <= 60 -- r1/r3/r4 law).
// ---------------------------------------------------------------------------
__global__ __launch_bounds__(256) void attn_kernel(
    const float* __restrict__ p,        // (NQ,3)
    const float* __restrict__ p2,       // (NKV,3)
    const int*   __restrict__ idx,      // (NQ,SS)
    const float* __restrict__ W1,       // (3,3)
    const float* __restrict__ b1,       // (3,)
    const float* __restrict__ bn_gamma,
    const float* __restrict__ bn_beta,
    const float* __restrict__ bn_mean,
    const float* __restrict__ bn_var,
    const float* __restrict__ W2,       // (16,3)
    const float* __restrict__ b2,       // (16,)
    const __hip_bfloat16* __restrict__ Qf,   // (NQ,128) bf16
    const __hip_bfloat16* __restrict__ KVf,  // (NKV,256) bf16 interleaved
    float* __restrict__ out)            // (NQ,CC) f32
{
    const int tid = blockIdx.x * 256 + threadIdx.x;
    if (tid >= NQ * GG) return;
    const int n = tid >> 3;
    const int g = tid & 7;

    // --- fold BN into the 3x3 conv ---
    float fw1[3][3], fb1[3];
    #pragma unroll
    for (int j = 0; j < 3; ++j) {
        const float sc = bn_gamma[j] * rsqrtf(bn_var[j] + 1e-5f);
        #pragma unroll
        for (int k = 0; k < 3; ++k) fw1[j][k] = W1[j*3 + k] * sc;
        fb1[j] = (b1[j] - bn_mean[j]) * sc + bn_beta[j];
    }
    const float w2q0 = W2[g*3+0],     w2q1 = W2[g*3+1],     w2q2 = W2[g*3+2];
    const float w2k0 = W2[(g+8)*3+0], w2k1 = W2[(g+8)*3+1], w2k2 = W2[(g+8)*3+2];
    const float b2q = b2[g], b2k = b2[g+8];

    const float px = p[(size_t)n*3+0];
    const float py = p[(size_t)n*3+1];
    const float pz = p[(size_t)n*3+2];

    // --- neighbor indices (16 ints = 64B aligned) ---
    int nbr[SS];
    {
        const i32x4* ip = reinterpret_cast<const i32x4*>(idx + (size_t)n * SS);
        i32x4 i0 = ip[0], i1 = ip[1], i2 = ip[2], i3 = ip[3];
        nbr[0]=i0[0]; nbr[1]=i0[1]; nbr[2]=i0[2]; nbr[3]=i0[3];
        nbr[4]=i1[0]; nbr[5]=i1[1]; nbr[6]=i1[2]; nbr[7]=i1[3];
        nbr[8]=i2[0]; nbr[9]=i2[1]; nbr[10]=i2[2]; nbr[11]=i2[3];
        nbr[12]=i3[0]; nbr[13]=i3[1]; nbr[14]=i3[2]; nbr[15]=i3[3];
    }

    // --- query fragment for this group ---
    float q[CSH];
    load16bf(Qf + (size_t)n * CC + g * CSH, q);

    // --- single fused pass with online softmax ---
    float acc[CSH];
    #pragma unroll
    for (int c = 0; c < CSH; ++c) acc[c] = 0.f;
    float sum = 0.f;
    float m = -3.0e38f;

    #pragma unroll 4
    for (int s = 0; s < SS; ++s) {
        const int i = nbr[s];
        const __hip_bfloat16* kv = KVf + (size_t)i * (2 * CC) + g * CSH;

        float kk[CSH], vv[CSH];
        load16bf(kv, kk);            // K slice at +0
        load16bf(kv + CC, vv);       // V slice at +256 B immediate

        const float rx = p2[(size_t)i*3+0] - px;
        const float ry = p2[(size_t)i*3+1] - py;
        const float rz = p2[(size_t)i*3+2] - pz;
        const float h0 = fmaxf(fw1[0][0]*rx + fw1[0][1]*ry + fw1[0][2]*rz + fb1[0], 0.f);
        const float h1 = fmaxf(fw1[1][0]*rx + fw1[1][1]*ry + fw1[1][2]*rz + fb1[1], 0.f);
        const float h2 = fmaxf(fw1[2][0]*rx + fw1[2][1]*ry + fw1[2][2]*rz + fb1[2], 0.f);
        const float prq = w2q0*h0 + w2q1*h1 + w2q2*h2 + b2q;
        const float prk = w2k0*h0 + w2k1*h1 + w2k2*h2 + b2k;

        float d = 0.f;
        #pragma unroll
        for (int c = 0; c < CSH; ++c) d += (kk[c] + prk) * (q[c] + prq);
        d *= 0.25f;   // 1/sqrt(CS) = 0.25

        const float mnew = fmaxf(m, d);
        const float corr = __expf(m - mnew);   // 1.0 when max unchanged
        const float w    = __expf(d - mnew);
        sum = sum * corr + w;
        #pragma unroll
        for (int c = 0; c < CSH; ++c) acc[c] = acc[c] * corr + w * vv[c];
        m = mnew;
    }

    const float inv = 1.f / sum;

    // --- store 16 f32 (64B; 8 lanes of one n cover 512B contiguous) ---
    f32x4* op = reinterpret_cast<f32x4*>(out + (size_t)n * CC + g * CSH);
    f32x4 o0 = {acc[0]*inv,  acc[1]*inv,  acc[2]*inv,  acc[3]*inv};
    f32x4 o1 = {acc[4]*inv,  acc[5]*inv,  acc[6]*inv,  acc[7]*inv};
    f32x4 o2 = {acc[8]*inv,  acc[9]*inv,  acc[10]*inv, acc[11]*inv};
    f32x4 o3 = {acc[12]*inv, acc[13]*inv, acc[14]*inv, acc[15]*inv};
    op[0] = o0; op[1] = o1; op[2] = o2; op[3] = o3;
}

// ---------------------------------------------------------------------------
extern "C" void kernel_launch(void* const* d_in, const int* in_sizes, int n_in,
                              void* d_out, int out_size, void* d_ws, size_t ws_size,
                              hipStream_t stream) {
    const float* p   = (const float*)d_in[0];
    const float* x   = (const float*)d_in[1];
    const float* p2  = (const float*)d_in[2];
    const float* x2  = (const float*)d_in[3];
    const int*   idx = (const int*)d_in[4];
    const float* Wq  = (const float*)d_in[5];
    const float* bq  = (const float*)d_in[6];
    const float* Wk  = (const float*)d_in[7];
    const float* bk  = (const float*)d_in[8];
    const float* Wv  = (const float*)d_in[9];
    const float* bv  = (const float*)d_in[10];
    const float* W1  = (const float*)d_in[11];
    const float* b1  = (const float*)d_in[12];
    const float* bng = (const float*)d_in[13];
    const float* bnb = (const float*)d_in[14];
    const float* bnm = (const float*)d_in[15];
    const float* bnv = (const float*)d_in[16];
    const float* W2  = (const float*)d_in[17];
    const float* b2  = (const float*)d_in[18];
    float* out = (float*)d_out;

    // workspace: Wp (96 KB, 16B-aligned) | Qf (12.8 MB) | KVf (25.6 MB)
    __hip_bfloat16* Wp  = (__hip_bfloat16*)d_ws;
    __hip_bfloat16* Qf  = Wp + 3 * 16384;             // 98304 B offset (16B-aligned)
    __hip_bfloat16* KVf = Qf + (size_t)NQ * CC;

    // one-time W pre-permutation (bf16, lchunk order): 3 blocks, ~3 us
    wprep<<<3, 256, 0, stream>>>(Wq, Wk, Wv, Wp);

    // 50000 rows / 128 rows-per-block = 391 blocks; y-dim = projection (Q,K,V)
    qkv_gemm<<<dim3(391, 3), 256, 0, stream>>>(
        x, x2, Wp, bq, bk, bv, Qf, KVf);

    // 50000 * 8 groups = 400000 threads -> 1563 blocks (tail returns early)
    attn_kernel<<<(NQ * GG + 255) / 256, 256, 0, stream>>>(
        p, p2, idx, W1, b1, bng, bnb, bnm, bnv, W2, b2, Qf, KVf, out);
}

// Round 9
// 207.761 us; speedup vs baseline: 1.2901x; 1.0158x over previous
//
#include <hip/hip_runtime.h>
#include <hip/hip_bf16.h>

#define NQ   50000
#define NKV  50000
#define CC   128
#define GG   8
#define SS   16
#define CSH  16

typedef short    bf16x8 __attribute__((ext_vector_type(8)));
typedef float    f32x4  __attribute__((ext_vector_type(4)));
typedef unsigned u32x4  __attribute__((ext_vector_type(4)));
typedef unsigned u32x2  __attribute__((ext_vector_type(2)));
typedef int      i32x4  __attribute__((ext_vector_type(4)));

__device__ __forceinline__ float bf_lo(unsigned u){ union{unsigned x; float f;} v; v.x = u << 16;        return v.f; }
__device__ __forceinline__ float bf_hi(unsigned u){ union{unsigned x; float f;} v; v.x = u & 0xffff0000u; return v.f; }
__device__ __forceinline__ unsigned short f2bfu(float f){
    __hip_bfloat16 h = __float2bfloat16(f);
    return *reinterpret_cast<unsigned short*>(&h);
}
__device__ __forceinline__ short f2bfs(float f){
    __hip_bfloat16 h = __float2bfloat16(f);
    return *reinterpret_cast<short*>(&h);
}

// Load 16 contiguous bf16 (32B, >=16B aligned) -> 16 fp32
__device__ __forceinline__ void load16bf(const __hip_bfloat16* ptr, float* o){
    const u32x4* p4 = reinterpret_cast<const u32x4*>(ptr);
    u32x4 a = p4[0]; u32x4 b = p4[1];
    o[0]=bf_lo(a[0]);  o[1]=bf_hi(a[0]);  o[2]=bf_lo(a[1]);  o[3]=bf_hi(a[1]);
    o[4]=bf_lo(a[2]);  o[5]=bf_hi(a[2]);  o[6]=bf_lo(a[3]);  o[7]=bf_hi(a[3]);
    o[8]=bf_lo(b[0]);  o[9]=bf_hi(b[0]);  o[10]=bf_lo(b[1]); o[11]=bf_hi(b[1]);
    o[12]=bf_lo(b[2]); o[13]=bf_hi(b[2]); o[14]=bf_lo(b[3]); o[15]=bf_hi(b[3]);
}

// Load 8 contiguous f32 (32B), convert to bf16x8 fragment
__device__ __forceinline__ bf16x8 cvt8(const float* p){
    const f32x4* q = reinterpret_cast<const f32x4*>(p);
    f32x4 u = q[0], v = q[1];
    bf16x8 r;
    r[0]=f2bfs(u[0]); r[1]=f2bfs(u[1]); r[2]=f2bfs(u[2]); r[3]=f2bfs(u[3]);
    r[4]=f2bfs(v[0]); r[5]=f2bfs(v[1]); r[6]=f2bfs(v[2]); r[7]=f2bfs(v[3]);
    return r;
}

// ---------------------------------------------------------------------------
// Kernel 1: Q/K/V projections, gridDim.y = 3 selects projection (0=Q,1=K,2=V).
// Round-9: REVERTED to the r2 proven form (inline f32->bf16 VALU staging).
// r8 post-mortem: pre-permuted-W + global_load_lds was net zero -- the extra
// wprep launch (~3-4 us) exactly canceled the staging savings, i.e. W staging
// was never qkv's bottleneck. Keep the simpler 2-launch pipeline.
// K/V interleaved rows: [K 0..127 | V 128..255].
// ---------------------------------------------------------------------------
__global__ __launch_bounds__(256) void qkv_gemm(
    const float* __restrict__ x,
    const float* __restrict__ x2,
    const float* __restrict__ Wq, const float* __restrict__ Wk,
    const float* __restrict__ Wv,
    const float* __restrict__ bq, const float* __restrict__ bk,
    const float* __restrict__ bv,
    __hip_bfloat16* __restrict__ Qf,     // (NQ, 128)
    __hip_bfloat16* __restrict__ KVf)    // (NKV, 256) interleaved K|V
{
    __shared__ short lds16[16384];   // 32 KB

    const int tid  = threadIdx.x;
    const int wave = tid >> 6;
    const int lane = tid & 63;
    const int r    = lane & 15;
    const int kq   = lane >> 4;
    const int base = blockIdx.x * 128 + wave * 32;   // this wave's 32 rows
    const int proj = blockIdx.y;                     // 0=Q 1=K 2=V (uniform)

    const float* src  = (proj == 0) ? x  : x2;
    const float* W    = (proj == 0) ? Wq : (proj == 1 ? Wk : Wv);
    const float* bias = (proj == 0) ? bq : (proj == 1 ? bk : bv);
    short* dstb   = (proj == 0) ? (short*)Qf : (short*)KVf;
    const int dstride = (proj == 0) ? CC : 2 * CC;
    const int hoff    = (proj == 2) ? CC : 0;

    // load this wave's 32 source rows as B-fragments (2 m-tiles x 4 k-blocks)
    bf16x8 bfrag[2][4];
    #pragma unroll
    for (int mt = 0; mt < 2; ++mt) {
        int row = base + mt * 16 + r;
        if (row >= NQ) row = NQ - 1;           // clamp; stores guarded
        const float* xr = src + (size_t)row * CC + kq * 8;
        #pragma unroll
        for (int kb = 0; kb < 4; ++kb)
            bfrag[mt][kb] = cvt8(xr + kb * 32);
    }

    // stage one 128x128 f32 W into LDS (bf16, MFMA A-fragment order)
    #pragma unroll
    for (int i = 0; i < 8; ++i) {
        const int o   = i * 2048 + tid * 8;    // linear f32 offset in W
        const bf16x8 v = cvt8(W + o);
        const int row = o >> 7, col = o & 127;
        const int lchunk = (((row >> 4) * 4 + (col >> 5)) << 6)
                         + (((col >> 3) & 3) << 4) + (row & 15);
        *reinterpret_cast<bf16x8*>(&lds16[lchunk * 8]) = v;
    }
    __syncthreads();

    // 8 column tiles: LDS A-frags x register B-frags -> 2x f32x4 acc -> store
    #pragma unroll
    for (int t = 0; t < 8; ++t) {
        bf16x8 af[4];
        #pragma unroll
        for (int kb = 0; kb < 4; ++kb)
            af[kb] = *reinterpret_cast<const bf16x8*>(
                &lds16[(((t * 4 + kb) << 6) + lane) * 8]);

        f32x4 acc0 = {0.f,0.f,0.f,0.f}, acc1 = {0.f,0.f,0.f,0.f};
        #pragma unroll
        for (int kb = 0; kb < 4; ++kb) {
            acc0 = __builtin_amdgcn_mfma_f32_16x16x32_bf16(af[kb], bfrag[0][kb], acc0, 0, 0, 0);
            acc1 = __builtin_amdgcn_mfma_f32_16x16x32_bf16(af[kb], bfrag[1][kb], acc1, 0, 0, 0);
        }

        const f32x4 bi = *reinterpret_cast<const f32x4*>(bias + t * 16 + kq * 4);
        #pragma unroll
        for (int mt = 0; mt < 2; ++mt) {
            const int row = base + mt * 16 + r;
            if (row < NQ) {
                const f32x4 a = mt ? acc1 : acc0;
                u32x2 pk;
                pk[0] = (unsigned)f2bfu(a[0] + bi[0]) | ((unsigned)f2bfu(a[1] + bi[1]) << 16);
                pk[1] = (unsigned)f2bfu(a[2] + bi[2]) | ((unsigned)f2bfu(a[3] + bi[3]) << 16);
                *reinterpret_cast<u32x2*>(
                    dstb + (size_t)row * dstride + hoff + t * 16 + kq * 4) = pk;
            }
        }
    }
}

// ---------------------------------------------------------------------------
// Kernel 2: fused gather + positional MLP + grouped attention -- r0 online-
// softmax form, best measured (r8: 62.7-63.2 us, VGPR 56, occ ~32%).
// Ceiling evidence (r0/r2/r4/r7): five structures pin at 3.1-3.5 TB/s on the
// random 512B-granule gather; duration insensitive to MLP depth & occupancy.
// attn is at the gather-fabric ceiling; demand is minimal & fully coalesced
// (8 lanes/n cover the whole KV row).
// Kept: shifted exp (PE term ~250 overflows unshifted), online max chain
// (the only structure that keeps VGPR <= 60 -- r1/r3/r4 law).
// ---------------------------------------------------------------------------
__global__ __launch_bounds__(256) void attn_kernel(
    const float* __restrict__ p,        // (NQ,3)
    const float* __restrict__ p2,       // (NKV,3)
    const int*   __restrict__ idx,      // (NQ,SS)
    const float* __restrict__ W1,       // (3,3)
    const float* __restrict__ b1,       // (3,)
    const float* __restrict__ bn_gamma,
    const float* __restrict__ bn_beta,
    const float* __restrict__ bn_mean,
    const float* __restrict__ bn_var,
    const float* __restrict__ W2,       // (16,3)
    const float* __restrict__ b2,       // (16,)
    const __hip_bfloat16* __restrict__ Qf,   // (NQ,128) bf16
    const __hip_bfloat16* __restrict__ KVf,  // (NKV,256) bf16 interleaved
    float* __restrict__ out)            // (NQ,CC) f32
{
    const int tid = blockIdx.x * 256 + threadIdx.x;
    if (tid >= NQ * GG) return;
    const int n = tid >> 3;
    const int g = tid & 7;

    // --- fold BN into the 3x3 conv ---
    float fw1[3][3], fb1[3];
    #pragma unroll
    for (int j = 0; j < 3; ++j) {
        const float sc = bn_gamma[j] * rsqrtf(bn_var[j] + 1e-5f);
        #pragma unroll
        for (int k = 0; k < 3; ++k) fw1[j][k] = W1[j*3 + k] * sc;
        fb1[j] = (b1[j] - bn_mean[j]) * sc + bn_beta[j];
    }
    const float w2q0 = W2[g*3+0],     w2q1 = W2[g*3+1],     w2q2 = W2[g*3+2];
    const float w2k0 = W2[(g+8)*3+0], w2k1 = W2[(g+8)*3+1], w2k2 = W2[(g+8)*3+2];
    const float b2q = b2[g], b2k = b2[g+8];

    const float px = p[(size_t)n*3+0];
    const float py = p[(size_t)n*3+1];
    const float pz = p[(size_t)n*3+2];

    // --- neighbor indices (16 ints = 64B aligned) ---
    int nbr[SS];
    {
        const i32x4* ip = reinterpret_cast<const i32x4*>(idx + (size_t)n * SS);
        i32x4 i0 = ip[0], i1 = ip[1], i2 = ip[2], i3 = ip[3];
        nbr[0]=i0[0]; nbr[1]=i0[1]; nbr[2]=i0[2]; nbr[3]=i0[3];
        nbr[4]=i1[0]; nbr[5]=i1[1]; nbr[6]=i1[2]; nbr[7]=i1[3];
        nbr[8]=i2[0]; nbr[9]=i2[1]; nbr[10]=i2[2]; nbr[11]=i2[3];
        nbr[12]=i3[0]; nbr[13]=i3[1]; nbr[14]=i3[2]; nbr[15]=i3[3];
    }

    // --- query fragment for this group ---
    float q[CSH];
    load16bf(Qf + (size_t)n * CC + g * CSH, q);

    // --- single fused pass with online softmax ---
    float acc[CSH];
    #pragma unroll
    for (int c = 0; c < CSH; ++c) acc[c] = 0.f;
    float sum = 0.f;
    float m = -3.0e38f;

    #pragma unroll 4
    for (int s = 0; s < SS; ++s) {
        const int i = nbr[s];
        const __hip_bfloat16* kv = KVf + (size_t)i * (2 * CC) + g * CSH;

        float kk[CSH], vv[CSH];
        load16bf(kv, kk);            // K slice at +0
        load16bf(kv + CC, vv);       // V slice at +256 B immediate

        const float rx = p2[(size_t)i*3+0] - px;
        const float ry = p2[(size_t)i*3+1] - py;
        const float rz = p2[(size_t)i*3+2] - pz;
        const float h0 = fmaxf(fw1[0][0]*rx + fw1[0][1]*ry + fw1[0][2]*rz + fb1[0], 0.f);
        const float h1 = fmaxf(fw1[1][0]*rx + fw1[1][1]*ry + fw1[1][2]*rz + fb1[1], 0.f);
        const float h2 = fmaxf(fw1[2][0]*rx + fw1[2][1]*ry + fw1[2][2]*rz + fb1[2], 0.f);
        const float prq = w2q0*h0 + w2q1*h1 + w2q2*h2 + b2q;
        const float prk = w2k0*h0 + w2k1*h1 + w2k2*h2 + b2k;

        float d = 0.f;
        #pragma unroll
        for (int c = 0; c < CSH; ++c) d += (kk[c] + prk) * (q[c] + prq);
        d *= 0.25f;   // 1/sqrt(CS) = 0.25

        const float mnew = fmaxf(m, d);
        const float corr = __expf(m - mnew);   // 1.0 when max unchanged
        const float w    = __expf(d - mnew);
        sum = sum * corr + w;
        #pragma unroll
        for (int c = 0; c < CSH; ++c) acc[c] = acc[c] * corr + w * vv[c];
        m = mnew;
    }

    const float inv = 1.f / sum;

    // --- store 16 f32 (64B; 8 lanes of one n cover 512B contiguous) ---
    f32x4* op = reinterpret_cast<f32x4*>(out + (size_t)n * CC + g * CSH);
    f32x4 o0 = {acc[0]*inv,  acc[1]*inv,  acc[2]*inv,  acc[3]*inv};
    f32x4 o1 = {acc[4]*inv,  acc[5]*inv,  acc[6]*inv,  acc[7]*inv};
    f32x4 o2 = {acc[8]*inv,  acc[9]*inv,  acc[10]*inv, acc[11]*inv};
    f32x4 o3 = {acc[12]*inv, acc[13]*inv, acc[14]*inv, acc[15]*inv};
    op[0] = o0; op[1] = o1; op[2] = o2; op[3] = o3;
}

// ---------------------------------------------------------------------------
extern "C" void kernel_launch(void* const* d_in, const int* in_sizes, int n_in,
                              void* d_out, int out_size, void* d_ws, size_t ws_size,
                              hipStream_t stream) {
    const float* p   = (const float*)d_in[0];
    const float* x   = (const float*)d_in[1];
    const float* p2  = (const float*)d_in[2];
    const float* x2  = (const float*)d_in[3];
    const int*   idx = (const int*)d_in[4];
    const float* Wq  = (const float*)d_in[5];
    const float* bq  = (const float*)d_in[6];
    const float* Wk  = (const float*)d_in[7];
    const float* bk  = (const float*)d_in[8];
    const float* Wv  = (const float*)d_in[9];
    const float* bv  = (const float*)d_in[10];
    const float* W1  = (const float*)d_in[11];
    const float* b1  = (const float*)d_in[12];
    const float* bng = (const float*)d_in[13];
    const float* bnb = (const float*)d_in[14];
    const float* bnm = (const float*)d_in[15];
    const float* bnv = (const float*)d_in[16];
    const float* W2  = (const float*)d_in[17];
    const float* b2  = (const float*)d_in[18];
    float* out = (float*)d_out;

    // workspace: Qf (12.8 MB) | KVf interleaved (25.6 MB)
    __hip_bfloat16* Qf  = (__hip_bfloat16*)d_ws;
    __hip_bfloat16* KVf = Qf + (size_t)NQ * CC;

    // 50000 rows / 128 rows-per-block = 391 blocks; y-dim = projection (Q,K,V)
    qkv_gemm<<<dim3(391, 3), 256, 0, stream>>>(
        x, x2, Wq, Wk, Wv, bq, bk, bv, Qf, KVf);

    // 50000 * 8 groups = 400000 threads -> 1563 blocks (tail returns early)
    attn_kernel<<<(NQ * GG + 255) / 256, 256, 0, stream>>>(
        p, p2, idx, W1, b1, bng, bnb, bnm, bnv, W2, b2, Qf, KVf, out);
}